// Round 1
// baseline (1616.292 us; speedup 1.0000x reference)
//
#include <hip/hip_runtime.h>
#include <math.h>

// Problem constants
#define Bz  16
#define Dz  512
#define Tz  4096
#define NCB 9
#define Kz  1024
#define CD  8

// Output layout (floats): z_q | codes | latents | cl | cbl
static const unsigned long long OZQ   = 0ull;
static const unsigned long long OCODE = 33554432ull;             // 16*512*4096
static const unsigned long long OLAT  = 34144256ull;             // + 16*9*4096
static const unsigned long long OCL   = 38862848ull;             // + 16*72*4096

#define WS_CBN2_OFF (NCB * CD * Kz)   // ws: cbnT[9][8][1024] then cbn2[9][1024]

// ---------------------------------------------------------------------------
// Prep: normalized codebooks (transposed) + their squared norms; zero loss slots
// ---------------------------------------------------------------------------
__global__ __launch_bounds__(1024) void rvq_prep(const float* __restrict__ cb,
                                                 float* __restrict__ ws,
                                                 float* __restrict__ out) {
    const int i = blockIdx.x;    // codebook 0..8
    const int k = threadIdx.x;   // entry 0..1023
    const float* row = cb + ((size_t)i * Kz + k) * CD;
    float v[CD];
#pragma unroll
    for (int c = 0; c < CD; ++c) v[c] = row[c];
    float ss = 0.f;
#pragma unroll
    for (int c = 0; c < CD; ++c) ss += v[c] * v[c];
    const float den = fmaxf(sqrtf(ss), 1e-12f);   // F.normalize eps clamp
    float cb2 = 0.f;
#pragma unroll
    for (int c = 0; c < CD; ++c) {
        float e = v[c] / den;
        ws[((size_t)i * CD + c) * Kz + k] = e;     // cbnT[i][c][k]
        cb2 += e * e;
    }
    ws[WS_CBN2_OFF + (size_t)i * Kz + k] = cb2;
    if (i == 0 && k == 0) { out[OCL] = 0.f; out[OCL + 1] = 0.f; }
}

// ---------------------------------------------------------------------------
// Main: one wave = 4 consecutive t-columns; lane owns d in [8*lane, 8*lane+8)
// All global I/O coalesced via LDS transpose staging.
// Register diet vs previous version:
//   - no zorig[4][8]: z is re-read (coalesced) during the z_q writeback,
//     z_q = z - res_final. Trades ~134 MB HBM for 32 fewer live VGPRs.
//   - no en2 broadcast: en is l2-normalized, en.en is constant per column,
//     so argmin over k is unchanged if we score cb2 - 2*dot only.
// Goal: peak live set < 128 regs so __launch_bounds__(512,4) has NO scratch.
// ---------------------------------------------------------------------------
__global__ __launch_bounds__(512, 4) void rvq_main(
    const float* __restrict__ z,
    const float* __restrict__ w_in,
    const float* __restrict__ b_in,
    const float* __restrict__ w_out,
    const float* __restrict__ b_out,
    const float* __restrict__ cb,
    const float* __restrict__ ws,
    float* __restrict__ out)
{
    // LDS
    __shared__ float s_win[64 * 68];       // 17408 B  w_in pad-swizzled
    __shared__ float s_cbnT[8 * 64 * 20];  // 40960 B  normalized codebook^T
    __shared__ float s_cbn2[Kz];           //  4096 B
    __shared__ float s_tr[32 * 68];        //  8704 B  transpose chunk (64 rows x 32 cols)
    __shared__ float s_lat[8 * 33];        //  1056 B  per-step latents stage
    __shared__ float s_code[NCB * 32];     //  1152 B  codes stage
    __shared__ float s_red[8];
    // total ~73.4 KB -> 2 blocks/CU

    const int tid  = threadIdx.x;
    const int wave = tid >> 6;
    const int lane = tid & 63;
    const int bb   = blockIdx.x;                 // 0..2047
    const int b    = bb >> 7;                    // batch
    const int t0blk = (bb & 127) << 5;           // block's 32-column base
    const int mycol = lane & 3;

    const size_t zbase = (size_t)b * Dz * Tz + t0blk;

    // ---- coalesced z load -> LDS transpose -> registers (directly into res4) ----
    float res4[4][8];
#pragma unroll 1
    for (int c = 0; c < 8; ++c) {
        {
            const int r = tid >> 3;              // 0..63
            const int u = (tid & 7) * 4;         // 0..28
            float4 v = *(const float4*)(z + zbase + (size_t)(c * 64 + r) * Tz + u);
            s_tr[(u + 0) * 68 + r] = v.x;
            s_tr[(u + 1) * 68 + r] = v.y;
            s_tr[(u + 2) * 68 + r] = v.z;
            s_tr[(u + 3) * 68 + r] = v.w;
        }
        __syncthreads();
        if ((lane >> 3) == c) {
            const int lr = (lane & 7) * 8;
#pragma unroll
            for (int col = 0; col < 4; ++col)
#pragma unroll
                for (int j = 0; j < 8; ++j)
                    res4[col][j] = s_tr[(wave * 4 + col) * 68 + lr + j];
        }
        __syncthreads();
    }

    float lsum = 0.f;

    for (int i = 0; i < NCB; ++i) {
        __syncthreads();   // previous step's LDS reads done
        // ---- flush previous step's latents (coalesced 128B rows) ----
        if (i > 0 && tid < 256) {
            const int c2 = tid >> 5, u = tid & 31;
            out[OLAT + ((size_t)b * 72 + (i - 1) * 8 + c2) * Tz + t0blk + u] =
                s_lat[c2 * 33 + u];
        }
        // ---- stage w_in / cbnT / cbn2 ----
        {
            const float4* src = (const float4*)(w_in + (size_t)i * 4096);
#pragma unroll
            for (int it = 0; it < 2; ++it) {
                int e4 = tid + it * 512;          // 0..1023
                float4 v = src[e4];
                int e = e4 * 4, c = e >> 9, d = e & 511;
                *(float4*)&s_win[(d >> 3) * 68 + c * 8 + (d & 7)] = v;
            }
            const float4* srcT = (const float4*)(ws + (size_t)i * 8192);
#pragma unroll
            for (int it = 0; it < 4; ++it) {
                int e4 = tid + it * 512;          // 0..2047
                float4 v = srcT[e4];
                int e = e4 * 4, c = e >> 10, k = e & 1023;
                *(float4*)&s_cbnT[c * 1280 + (k >> 4) * 20 + (k & 15)] = v;
            }
            if (tid < 256) {
                const float4* s2 = (const float4*)(ws + WS_CBN2_OFF + (size_t)i * Kz);
                ((float4*)s_cbn2)[tid] = s2[tid];
            }
        }
        __syncthreads();

        // ---- z_e = w_in @ residual + b_in : per-lane partials over its 8 d's ----
        float p[8][4];
#pragma unroll
        for (int c = 0; c < 8; ++c) {
            const float* wl = &s_win[lane * 68 + c * 8];
            float4 a = *(const float4*)wl;
            float4 b4 = *(const float4*)(wl + 4);
            float w8[8] = {a.x, a.y, a.z, a.w, b4.x, b4.y, b4.z, b4.w};
#pragma unroll
            for (int col = 0; col < 4; ++col) {
                float s = 0.f;
#pragma unroll
                for (int j = 0; j < 8; ++j) s = fmaf(w8[j], res4[col][j], s);
                p[c][col] = s;
            }
        }
        // quad all-reduce
#pragma unroll
        for (int c = 0; c < 8; ++c) {
#pragma unroll
            for (int col = 0; col < 4; ++col) {
                p[c][col] += __shfl_xor(p[c][col], 1, 64);
                p[c][col] += __shfl_xor(p[c][col], 2, 64);
            }
        }
        // specialize to own column, reduce across quads
        float z_own[8];
#pragma unroll
        for (int c = 0; c < 8; ++c) {
            float v = p[c][0];
            v = (mycol == 1) ? p[c][1] : v;
            v = (mycol == 2) ? p[c][2] : v;
            v = (mycol == 3) ? p[c][3] : v;
#pragma unroll
            for (int off = 4; off <= 32; off <<= 1) v += __shfl_xor(v, off, 64);
            z_own[c] = v + b_in[i * 8 + c];
        }

        // ---- latents stage to LDS (flushed next iteration) ----
        {
            int cc = lane >> 2;
            float v = z_own[0];
#pragma unroll
            for (int c = 1; c < 8; ++c) v = (cc == c) ? z_own[c] : v;
            if (lane < 32) s_lat[cc * 33 + wave * 4 + mycol] = v;
        }

        // ---- l2-normalize own column's z_e ----
        float ss = 0.f;
#pragma unroll
        for (int c = 0; c < 8; ++c) ss += z_own[c] * z_own[c];
        const float den = fmaxf(sqrtf(ss), 1e-12f);
        float en_own[8];
#pragma unroll
        for (int c = 0; c < 8; ++c) en_own[c] = z_own[c] / den;

        // broadcast all 4 columns' en to every lane
        // (en.en is constant per column -> irrelevant for argmin, not broadcast)
        float en4[4][8];
        const int qbase = lane & ~3;
#pragma unroll
        for (int g = 0; g < 4; ++g) {
#pragma unroll
            for (int c = 0; c < 8; ++c) en4[g][c] = __shfl(en_own[c], qbase + g, 64);
        }

        // ---- distance scoring: lane owns k in [16*lane, 16*lane+16) ----
        // score = cb2 - 2*dot  (en2 omitted: constant per column)
        float best[4]; int bidx[4];
#pragma unroll
        for (int g = 0; g < 4; ++g) { best[g] = 1e30f; bidx[g] = 0; }
#pragma unroll
        for (int mq = 0; mq < 4; ++mq) {
            float4 c2 = *(const float4*)&s_cbn2[lane * 16 + mq * 4];
            float dots[4][4];
#pragma unroll
            for (int g = 0; g < 4; ++g)
#pragma unroll
                for (int q = 0; q < 4; ++q) dots[g][q] = 0.f;
#pragma unroll
            for (int c = 0; c < 8; ++c) {
                float4 v = *(const float4*)&s_cbnT[c * 1280 + lane * 20 + mq * 4];
#pragma unroll
                for (int g = 0; g < 4; ++g) {
                    dots[g][0] = fmaf(en4[g][c], v.x, dots[g][0]);
                    dots[g][1] = fmaf(en4[g][c], v.y, dots[g][1]);
                    dots[g][2] = fmaf(en4[g][c], v.z, dots[g][2]);
                    dots[g][3] = fmaf(en4[g][c], v.w, dots[g][3]);
                }
            }
#pragma unroll
            for (int q = 0; q < 4; ++q) {
                const int kk = lane * 16 + mq * 4 + q;
                const float cb2q = (q == 0) ? c2.x : (q == 1) ? c2.y : (q == 2) ? c2.z : c2.w;
#pragma unroll
                for (int g = 0; g < 4; ++g) {
                    float dist = fmaf(-2.f, dots[g][q], cb2q);
                    if (dist < best[g]) { best[g] = dist; bidx[g] = kk; }   // first-min
                }
            }
        }
        // 64-lane argmin butterfly, tie -> smaller index
#pragma unroll
        for (int off = 1; off <= 32; off <<= 1) {
#pragma unroll
            for (int g = 0; g < 4; ++g) {
                float ob = __shfl_xor(best[g], off, 64);
                int   oi = __shfl_xor(bidx[g], off, 64);
                if (ob < best[g] || (ob == best[g] && oi < bidx[g])) {
                    best[g] = ob; bidx[g] = oi;
                }
            }
        }

        // ---- fetch raw codebook rows for the 4 winners ----
        float cbq[4][8];
#pragma unroll
        for (int g = 0; g < 4; ++g) {
            const float* cr = cb + ((size_t)i * Kz + bidx[g]) * CD;
            float4 a = *(const float4*)cr;
            float4 b4 = *(const float4*)(cr + 4);
            cbq[g][0] = a.x;  cbq[g][1] = a.y;  cbq[g][2] = a.z;  cbq[g][3] = a.w;
            cbq[g][4] = b4.x; cbq[g][5] = b4.y; cbq[g][6] = b4.z; cbq[g][7] = b4.w;
        }

        // ---- loss term ----
#pragma unroll
        for (int g = 0; g < 4; ++g) {
            if (lane == g) {
#pragma unroll
                for (int c = 0; c < 8; ++c) {
                    float dd = z_own[c] - cbq[g][c];
                    lsum = fmaf(dd, dd, lsum);
                }
            }
        }

        // ---- codes stage to LDS ----
        {
            float v = (float)bidx[0];
            v = (lane == 1) ? (float)bidx[1] : v;
            v = (lane == 2) ? (float)bidx[2] : v;
            v = (lane == 3) ? (float)bidx[3] : v;
            if (lane < 4) s_code[i * 32 + wave * 4 + lane] = v;
        }

        // ---- out_proj + residual update ----
        {
            const float* wo = w_out + (size_t)i * 4096 + (size_t)lane * 64;
            const float* bo = b_out + (size_t)i * Dz + lane * 8;
            float4 bA = *(const float4*)bo;
            float4 bB = *(const float4*)(bo + 4);
            float bv[8] = {bA.x, bA.y, bA.z, bA.w, bB.x, bB.y, bB.z, bB.w};
#pragma unroll
            for (int j = 0; j < 8; ++j) {
                float4 wa = *(const float4*)(wo + j * 8);
                float4 wb = *(const float4*)(wo + j * 8 + 4);
                float wr[8] = {wa.x, wa.y, wa.z, wa.w, wb.x, wb.y, wb.z, wb.w};
#pragma unroll
                for (int g = 0; g < 4; ++g) {
                    float s = 0.f;
#pragma unroll
                    for (int c = 0; c < 8; ++c) s = fmaf(wr[c], cbq[g][c], s);
                    res4[g][j] -= (s + bv[j]);
                }
            }
        }
    }

    // ---- flush last step's latents + all codes (coalesced) ----
    __syncthreads();
    if (tid < 256) {
        const int c2 = tid >> 5, u = tid & 31;
        out[OLAT + ((size_t)b * 72 + 8 * 8 + c2) * Tz + t0blk + u] = s_lat[c2 * 33 + u];
    }
    if (tid < NCB * 32) {
        const int i2 = tid >> 5, u = tid & 31;
        out[OCODE + ((size_t)b * NCB + i2) * Tz + t0blk + u] = s_code[i2 * 32 + u];
    }

    // ---- z_q = z - residual_final : res -> LDS transpose, re-read z, store ----
#pragma unroll 1
    for (int c = 0; c < 8; ++c) {
        if ((lane >> 3) == c) {
            const int lr = (lane & 7) * 8;
#pragma unroll
            for (int col = 0; col < 4; ++col)
#pragma unroll
                for (int j = 0; j < 8; ++j)
                    s_tr[(wave * 4 + col) * 68 + lr + j] = res4[col][j];
        }
        __syncthreads();
        {
            const int r = tid >> 3;
            const int u = (tid & 7) * 4;
            float4 zv = *(const float4*)(z + zbase + (size_t)(c * 64 + r) * Tz + u);
            float4 v;
            v.x = zv.x - s_tr[(u + 0) * 68 + r];
            v.y = zv.y - s_tr[(u + 1) * 68 + r];
            v.z = zv.z - s_tr[(u + 2) * 68 + r];
            v.w = zv.w - s_tr[(u + 3) * 68 + r];
            *(float4*)(out + OZQ + zbase + (size_t)(c * 64 + r) * Tz + u) = v;
        }
        __syncthreads();
    }

    // ---- loss reduction ----
#pragma unroll
    for (int off = 1; off <= 32; off <<= 1) lsum += __shfl_xor(lsum, off, 64);
    if (lane == 0) s_red[wave] = lsum;
    __syncthreads();
    if (tid == 0) {
        float t = 0.f;
#pragma unroll
        for (int w2 = 0; w2 < 8; ++w2) t += s_red[w2];
        t *= (1.f / 524288.f);   // /(16*8*4096)
        atomicAdd(&out[OCL], t);
        atomicAdd(&out[OCL + 1], t);
    }
}

// ---------------------------------------------------------------------------
extern "C" void kernel_launch(void* const* d_in, const int* in_sizes, int n_in,
                              void* d_out, int out_size, void* d_ws, size_t ws_size,
                              hipStream_t stream) {
    (void)in_sizes; (void)n_in; (void)out_size; (void)ws_size;
    const float* z     = (const float*)d_in[0];
    const float* w_in  = (const float*)d_in[1];
    const float* b_in  = (const float*)d_in[2];
    const float* w_out = (const float*)d_in[3];
    const float* b_out = (const float*)d_in[4];
    const float* cb    = (const float*)d_in[5];
    float* ws  = (float*)d_ws;
    float* out = (float*)d_out;

    rvq_prep<<<NCB, 1024, 0, stream>>>(cb, ws, out);
    rvq_main<<<2048, 512, 0, stream>>>(z, w_in, b_in, w_out, b_out, cb, ws, out);
}

// Round 3
// 1283.006 us; speedup vs baseline: 1.2598x; 1.2598x over previous
//
#include <hip/hip_runtime.h>
#include <math.h>

// Problem constants
#define Bz  16
#define Dz  512
#define Tz  4096
#define NCB 9
#define Kz  1024
#define CD  8

// Output layout (floats): z_q | codes | latents | cl | cbl
static const unsigned long long OZQ   = 0ull;
static const unsigned long long OCODE = 33554432ull;             // 16*512*4096
static const unsigned long long OLAT  = 34144256ull;             // + 16*9*4096
static const unsigned long long OCL   = 38862848ull;             // + 16*72*4096

#define WS_CBN2_OFF (NCB * CD * Kz)   // ws: cbnT[9][8][1024] then cbn2[9][1024]

// ---------------------------------------------------------------------------
// Prep: normalized codebooks (transposed) + their squared norms; zero loss slots
// ---------------------------------------------------------------------------
__global__ __launch_bounds__(1024) void rvq_prep(const float* __restrict__ cb,
                                                 float* __restrict__ ws,
                                                 float* __restrict__ out) {
    const int i = blockIdx.x;    // codebook 0..8
    const int k = threadIdx.x;   // entry 0..1023
    const float* row = cb + ((size_t)i * Kz + k) * CD;
    float v[CD];
#pragma unroll
    for (int c = 0; c < CD; ++c) v[c] = row[c];
    float ss = 0.f;
#pragma unroll
    for (int c = 0; c < CD; ++c) ss += v[c] * v[c];
    const float den = fmaxf(sqrtf(ss), 1e-12f);   // F.normalize eps clamp
    float cb2 = 0.f;
#pragma unroll
    for (int c = 0; c < CD; ++c) {
        float e = v[c] / den;
        ws[((size_t)i * CD + c) * Kz + k] = e;     // cbnT[i][c][k]
        cb2 += e * e;
    }
    ws[WS_CBN2_OFF + (size_t)i * Kz + k] = cb2;
    if (i == 0 && k == 0) { out[OCL] = 0.f; out[OCL + 1] = 0.f; }
}

// ---------------------------------------------------------------------------
// Main: one wave = 4 consecutive t-columns; lane owns d in [8*lane, 8*lane+8)
// All global I/O coalesced via LDS transpose staging.
//
// Occupancy/regalloc note: LDS (73.4 KB) caps us at 2 blocks/CU = 4 waves/EU.
// amdgpu_waves_per_eu(4,4) PINS the allocator to that occupancy so it gets the
// full 128-VGPR budget instead of targeting 8 waves/EU with a 64-reg budget
// and spilling ~70 dwords/thread/step to scratch (the observed ~2.5 GB of
// phantom HBM writes). Explicit attribute form (no __launch_bounds__ mix).
// ---------------------------------------------------------------------------
__global__
__attribute__((amdgpu_flat_work_group_size(512, 512), amdgpu_waves_per_eu(4, 4)))
void rvq_main(
    const float* __restrict__ z,
    const float* __restrict__ w_in,
    const float* __restrict__ b_in,
    const float* __restrict__ w_out,
    const float* __restrict__ b_out,
    const float* __restrict__ cb,
    const float* __restrict__ ws,
    float* __restrict__ out)
{
    // LDS
    __shared__ float s_win[64 * 68];       // 17408 B  w_in pad-swizzled
    __shared__ float s_cbnT[8 * 64 * 20];  // 40960 B  normalized codebook^T
    __shared__ float s_cbn2[Kz];           //  4096 B
    __shared__ float s_tr[32 * 68];        //  8704 B  transpose chunk (64 rows x 32 cols)
    __shared__ float s_lat[8 * 33];        //  1056 B  per-step latents stage
    __shared__ float s_code[NCB * 32];     //  1152 B  codes stage
    __shared__ float s_red[8];
    // total ~73.4 KB -> 2 blocks/CU

    const int tid  = threadIdx.x;
    const int wave = tid >> 6;
    const int lane = tid & 63;
    const int bb   = blockIdx.x;                 // 0..2047
    const int b    = bb >> 7;                    // batch
    const int t0blk = (bb & 127) << 5;           // block's 32-column base
    const int mycol = lane & 3;

    const size_t zbase = (size_t)b * Dz * Tz + t0blk;

    // ---- coalesced z load -> LDS transpose -> registers (directly into res4) ----
    float res4[4][8];
#pragma unroll 1
    for (int c = 0; c < 8; ++c) {
        {
            const int r = tid >> 3;              // 0..63
            const int u = (tid & 7) * 4;         // 0..28
            float4 v = *(const float4*)(z + zbase + (size_t)(c * 64 + r) * Tz + u);
            s_tr[(u + 0) * 68 + r] = v.x;
            s_tr[(u + 1) * 68 + r] = v.y;
            s_tr[(u + 2) * 68 + r] = v.z;
            s_tr[(u + 3) * 68 + r] = v.w;
        }
        __syncthreads();
        if ((lane >> 3) == c) {
            const int lr = (lane & 7) * 8;
#pragma unroll
            for (int col = 0; col < 4; ++col)
#pragma unroll
                for (int j = 0; j < 8; ++j)
                    res4[col][j] = s_tr[(wave * 4 + col) * 68 + lr + j];
        }
        __syncthreads();
    }

    float lsum = 0.f;

#pragma unroll 1
    for (int i = 0; i < NCB; ++i) {
        __syncthreads();   // previous step's LDS reads done
        // ---- flush previous step's latents (coalesced 128B rows) ----
        if (i > 0 && tid < 256) {
            const int c2 = tid >> 5, u = tid & 31;
            out[OLAT + ((size_t)b * 72 + (i - 1) * 8 + c2) * Tz + t0blk + u] =
                s_lat[c2 * 33 + u];
        }
        // ---- stage w_in / cbnT / cbn2 ----
        {
            const float4* src = (const float4*)(w_in + (size_t)i * 4096);
#pragma unroll
            for (int it = 0; it < 2; ++it) {
                int e4 = tid + it * 512;          // 0..1023
                float4 v = src[e4];
                int e = e4 * 4, c = e >> 9, d = e & 511;
                *(float4*)&s_win[(d >> 3) * 68 + c * 8 + (d & 7)] = v;
            }
            const float4* srcT = (const float4*)(ws + (size_t)i * 8192);
#pragma unroll
            for (int it = 0; it < 4; ++it) {
                int e4 = tid + it * 512;          // 0..2047
                float4 v = srcT[e4];
                int e = e4 * 4, c = e >> 10, k = e & 1023;
                *(float4*)&s_cbnT[c * 1280 + (k >> 4) * 20 + (k & 15)] = v;
            }
            if (tid < 256) {
                const float4* s2 = (const float4*)(ws + WS_CBN2_OFF + (size_t)i * Kz);
                ((float4*)s_cbn2)[tid] = s2[tid];
            }
        }
        __syncthreads();

        // ---- z_e = w_in @ residual + b_in ----
        // Per-c immediate reduction: transient is 4 regs (q[4]) instead of a
        // p[8][4]=32-reg peak.
        float z_own[8];
#pragma unroll
        for (int c = 0; c < 8; ++c) {
            const float* wl = &s_win[lane * 68 + c * 8];
            float4 a = *(const float4*)wl;
            float4 b4 = *(const float4*)(wl + 4);
            float w8[8] = {a.x, a.y, a.z, a.w, b4.x, b4.y, b4.z, b4.w};
            float q[4];
#pragma unroll
            for (int col = 0; col < 4; ++col) {
                float s = 0.f;
#pragma unroll
                for (int j = 0; j < 8; ++j) s = fmaf(w8[j], res4[col][j], s);
                q[col] = s;
            }
            // quad all-reduce (4 lanes of the quad hold 4 different d-ranges)
#pragma unroll
            for (int col = 0; col < 4; ++col) {
                q[col] += __shfl_xor(q[col], 1, 64);
                q[col] += __shfl_xor(q[col], 2, 64);
            }
            // specialize to own column, reduce across the 16 quads
            float v = q[0];
            v = (mycol == 1) ? q[1] : v;
            v = (mycol == 2) ? q[2] : v;
            v = (mycol == 3) ? q[3] : v;
#pragma unroll
            for (int off = 4; off <= 32; off <<= 1) v += __shfl_xor(v, off, 64);
            z_own[c] = v + b_in[i * 8 + c];
        }

        // ---- latents stage to LDS (flushed next iteration) ----
        {
            int cc = lane >> 2;
            float v = z_own[0];
#pragma unroll
            for (int c = 1; c < 8; ++c) v = (cc == c) ? z_own[c] : v;
            if (lane < 32) s_lat[cc * 33 + wave * 4 + mycol] = v;
        }

        // ---- l2-normalize own column's z_e ----
        float ss = 0.f;
#pragma unroll
        for (int c = 0; c < 8; ++c) ss += z_own[c] * z_own[c];
        const float den = fmaxf(sqrtf(ss), 1e-12f);
        float en_own[8];
#pragma unroll
        for (int c = 0; c < 8; ++c) en_own[c] = z_own[c] / den;

        // broadcast all 4 columns' en to every lane
        // (en.en is constant per column -> irrelevant for argmin, not broadcast)
        float en4[4][8];
        const int qbase = lane & ~3;
#pragma unroll
        for (int g = 0; g < 4; ++g) {
#pragma unroll
            for (int c = 0; c < 8; ++c) en4[g][c] = __shfl(en_own[c], qbase + g, 64);
        }

        // ---- distance scoring: lane owns k in [16*lane, 16*lane+16) ----
        // score = cb2 - 2*dot  (en2 omitted: constant per column)
        float best[4]; int bidx[4];
#pragma unroll
        for (int g = 0; g < 4; ++g) { best[g] = 1e30f; bidx[g] = 0; }
#pragma unroll
        for (int mq = 0; mq < 4; ++mq) {
            float4 c2 = *(const float4*)&s_cbn2[lane * 16 + mq * 4];
            float dots[4][4];
#pragma unroll
            for (int g = 0; g < 4; ++g)
#pragma unroll
                for (int q = 0; q < 4; ++q) dots[g][q] = 0.f;
#pragma unroll
            for (int c = 0; c < 8; ++c) {
                float4 v = *(const float4*)&s_cbnT[c * 1280 + lane * 20 + mq * 4];
#pragma unroll
                for (int g = 0; g < 4; ++g) {
                    dots[g][0] = fmaf(en4[g][c], v.x, dots[g][0]);
                    dots[g][1] = fmaf(en4[g][c], v.y, dots[g][1]);
                    dots[g][2] = fmaf(en4[g][c], v.z, dots[g][2]);
                    dots[g][3] = fmaf(en4[g][c], v.w, dots[g][3]);
                }
            }
#pragma unroll
            for (int q = 0; q < 4; ++q) {
                const int kk = lane * 16 + mq * 4 + q;
                const float cb2q = (q == 0) ? c2.x : (q == 1) ? c2.y : (q == 2) ? c2.z : c2.w;
#pragma unroll
                for (int g = 0; g < 4; ++g) {
                    float dist = fmaf(-2.f, dots[g][q], cb2q);
                    if (dist < best[g]) { best[g] = dist; bidx[g] = kk; }   // first-min
                }
            }
        }
        // 64-lane argmin butterfly, tie -> smaller index
#pragma unroll
        for (int off = 1; off <= 32; off <<= 1) {
#pragma unroll
            for (int g = 0; g < 4; ++g) {
                float ob = __shfl_xor(best[g], off, 64);
                int   oi = __shfl_xor(bidx[g], off, 64);
                if (ob < best[g] || (ob == best[g] && oi < bidx[g])) {
                    best[g] = ob; bidx[g] = oi;
                }
            }
        }

        // ---- fetch raw codebook rows for the 4 winners ----
        float cbq[4][8];
#pragma unroll
        for (int g = 0; g < 4; ++g) {
            const float* cr = cb + ((size_t)i * Kz + bidx[g]) * CD;
            float4 a = *(const float4*)cr;
            float4 b4 = *(const float4*)(cr + 4);
            cbq[g][0] = a.x;  cbq[g][1] = a.y;  cbq[g][2] = a.z;  cbq[g][3] = a.w;
            cbq[g][4] = b4.x; cbq[g][5] = b4.y; cbq[g][6] = b4.z; cbq[g][7] = b4.w;
        }

        // ---- loss term ----
#pragma unroll
        for (int g = 0; g < 4; ++g) {
            if (lane == g) {
#pragma unroll
                for (int c = 0; c < 8; ++c) {
                    float dd = z_own[c] - cbq[g][c];
                    lsum = fmaf(dd, dd, lsum);
                }
            }
        }

        // ---- codes stage to LDS ----
        {
            float v = (float)bidx[0];
            v = (lane == 1) ? (float)bidx[1] : v;
            v = (lane == 2) ? (float)bidx[2] : v;
            v = (lane == 3) ? (float)bidx[3] : v;
            if (lane < 4) s_code[i * 32 + wave * 4 + lane] = v;
        }

        // ---- out_proj + residual update ----
        {
            const float* wo = w_out + (size_t)i * 4096 + (size_t)lane * 64;
            const float* bo = b_out + (size_t)i * Dz + lane * 8;
            float4 bA = *(const float4*)bo;
            float4 bB = *(const float4*)(bo + 4);
            float bv[8] = {bA.x, bA.y, bA.z, bA.w, bB.x, bB.y, bB.z, bB.w};
#pragma unroll
            for (int j = 0; j < 8; ++j) {
                float4 wa = *(const float4*)(wo + j * 8);
                float4 wb = *(const float4*)(wo + j * 8 + 4);
                float wr[8] = {wa.x, wa.y, wa.z, wa.w, wb.x, wb.y, wb.z, wb.w};
#pragma unroll
                for (int g = 0; g < 4; ++g) {
                    float s = 0.f;
#pragma unroll
                    for (int c = 0; c < 8; ++c) s = fmaf(wr[c], cbq[g][c], s);
                    res4[g][j] -= (s + bv[j]);
                }
            }
        }
    }

    // ---- flush last step's latents + all codes (coalesced) ----
    __syncthreads();
    if (tid < 256) {
        const int c2 = tid >> 5, u = tid & 31;
        out[OLAT + ((size_t)b * 72 + 8 * 8 + c2) * Tz + t0blk + u] = s_lat[c2 * 33 + u];
    }
    if (tid < NCB * 32) {
        const int i2 = tid >> 5, u = tid & 31;
        out[OCODE + ((size_t)b * NCB + i2) * Tz + t0blk + u] = s_code[i2 * 32 + u];
    }

    // ---- z_q = z - residual_final : res -> LDS transpose, re-read z, store ----
#pragma unroll 1
    for (int c = 0; c < 8; ++c) {
        if ((lane >> 3) == c) {
            const int lr = (lane & 7) * 8;
#pragma unroll
            for (int col = 0; col < 4; ++col)
#pragma unroll
                for (int j = 0; j < 8; ++j)
                    s_tr[(wave * 4 + col) * 68 + lr + j] = res4[col][j];
        }
        __syncthreads();
        {
            const int r = tid >> 3;
            const int u = (tid & 7) * 4;
            float4 zv = *(const float4*)(z + zbase + (size_t)(c * 64 + r) * Tz + u);
            float4 v;
            v.x = zv.x - s_tr[(u + 0) * 68 + r];
            v.y = zv.y - s_tr[(u + 1) * 68 + r];
            v.z = zv.z - s_tr[(u + 2) * 68 + r];
            v.w = zv.w - s_tr[(u + 3) * 68 + r];
            *(float4*)(out + OZQ + zbase + (size_t)(c * 64 + r) * Tz + u) = v;
        }
        __syncthreads();
    }

    // ---- loss reduction ----
#pragma unroll
    for (int off = 1; off <= 32; off <<= 1) lsum += __shfl_xor(lsum, off, 64);
    if (lane == 0) s_red[wave] = lsum;
    __syncthreads();
    if (tid == 0) {
        float t = 0.f;
#pragma unroll
        for (int w2 = 0; w2 < 8; ++w2) t += s_red[w2];
        t *= (1.f / 524288.f);   // /(16*8*4096)
        atomicAdd(&out[OCL], t);
        atomicAdd(&out[OCL + 1], t);
    }
}

// ---------------------------------------------------------------------------
extern "C" void kernel_launch(void* const* d_in, const int* in_sizes, int n_in,
                              void* d_out, int out_size, void* d_ws, size_t ws_size,
                              hipStream_t stream) {
    (void)in_sizes; (void)n_in; (void)out_size; (void)ws_size;
    const float* z     = (const float*)d_in[0];
    const float* w_in  = (const float*)d_in[1];
    const float* b_in  = (const float*)d_in[2];
    const float* w_out = (const float*)d_in[3];
    const float* b_out = (const float*)d_in[4];
    const float* cb    = (const float*)d_in[5];
    float* ws  = (float*)d_ws;
    float* out = (float*)d_out;

    rvq_prep<<<NCB, 1024, 0, stream>>>(cb, ws, out);
    rvq_main<<<2048, 512, 0, stream>>>(z, w_in, b_in, w_out, b_out, cb, ws, out);
}